// Round 17
// baseline (399.117 us; speedup 1.0000x reference)
//
#include <hip/hip_runtime.h>
#include <hip/hip_bf16.h>
#include <math.h>

// ---------------------------------------------------------------------------
// sMLP4 round 26: gemm2 4-kc phases -- 32 barriers -> 9 (single change).
// r25 post-mortem: triple-buffering NULL (392 vs 390) => staging-load
// latency is not gemm2's cost. Remaining suspect per pre-commit: the
// BARRIER COUNT -- 32 __syncthreads/block x ~6.25 block-rounds/CU = 200
// barrier instances/CU, each a full vmcnt(0) drain of all in-flight
// prefetches across 12 waves (~400cyc) ~= 33us of the ~55us gap between
// measured (~85us) and pipe work (~30 MFMA + 20 LDS).
// Fix: stage 4 kc per buffer (bls[2][4][5][64] = 40,960B; 3 blocks/CU =
// 123KB <= 160KB LDS). Phase: write next buf from staged regs; issue loads
// 2 phases ahead; compute 4 kc; ONE barrier. 32 -> 9 barriers; write slack
// ~1 full phase (>= L2 latency) as side effect. Hazards: write buf(p+1)&1
// after the p-1 barrier (readers done); p+1 reads behind the p barrier.
// Everything else byte-identical to r25. fused1 FROZEN (r19 text).
// Trajectory bit-identical to rounds 10-25 (absmax 0.0009765625).
// ---------------------------------------------------------------------------

#define NSTEPS 50
#define KC1 13                     // K chunks of 64 for layer 1 (832 >= 784)
#define NSL 5                      // digit slices (digits 1..5 of 2^48 fix-pt)

typedef __attribute__((ext_vector_type(4)))  int i32x4;
typedef __attribute__((ext_vector_type(16))) int i32x16;

// fixed workspace layout (bytes, all 256-aligned)
#define OFF_B1     0ull            // i8 [64*13*5*64*16] = 4,259,840
#define OFF_B2     4259840ull      // i8 [5*4*32*1024]   =   655,360
#define OFF_AF     4915200ull      // i8 [50*64*13*64*16]= 42,598,400
#define OFF_H1SC   47513600ull     // i8 [50*64*1024*16] = 52,428,800
#define OFF_T2L    99942400ull     // i32[50*1024*128]   = 26,214,400
#define OFF_T2H    126156800ull    // i16[50*1024*128]   = 13,107,200
#define OFF_H2M    139264000ull    // f64[1024*128]      = 1,048,576
#define OFF_H2S    140312576ull    // i8 [1024*128]      =   131,072
#define OFF_ACC    140443648ull    // f64[1024*10]       =    81,920
#define OFF_BAR    140525568ull    // u32[128] lockstep counters (512 B)
#define WS_END     140526080ull    // 134 MB

#define PREP_BLOCKS 3840           // (851,968 + 131,072) / 256
#define SPK_BLOCKS 10400           // 50*64*13 groups / 4

// ---------------------------------------------------------------------------
// threefry2x32, key (0,42), partitionable mode: bits(i) = x0^x1 on ctr (0,i)
// ---------------------------------------------------------------------------
__device__ __forceinline__ unsigned int rotl32(unsigned int v, int d) {
#if __has_builtin(__builtin_amdgcn_alignbit)
  return __builtin_amdgcn_alignbit(v, v, (unsigned int)(32 - d));
#else
  return (v << d) | (v >> (32 - d));
#endif
}

__device__ __forceinline__ unsigned int tf_bits(unsigned int i) {
  const unsigned int ks0 = 0u;
  const unsigned int ks1 = 42u;
  const unsigned int ks2 = 0x1BD11BDAu ^ 0u ^ 42u;
  unsigned int x0 = 0u + ks0;
  unsigned int x1 = i + ks1;
#define TF_RND(r) { x0 += x1; x1 = rotl32(x1, r); x1 ^= x0; }
  TF_RND(13) TF_RND(15) TF_RND(26) TF_RND(6)
  x0 += ks1; x1 += ks2 + 1u;
  TF_RND(17) TF_RND(29) TF_RND(16) TF_RND(24)
  x0 += ks2; x1 += ks0 + 2u;
  TF_RND(13) TF_RND(15) TF_RND(26) TF_RND(6)
  x0 += ks0; x1 += ks1 + 3u;
  TF_RND(17) TF_RND(29) TF_RND(16) TF_RND(24)
  x0 += ks1; x1 += ks2 + 4u;
  TF_RND(13) TF_RND(15) TF_RND(26) TF_RND(6)
  x0 += ks2; x1 += ks0 + 5u;
#undef TF_RND
  return x0 ^ x1;
}

// ---------------------------------------------------------------------------
// one spikegen group: A-frag (16x16x64) for (t, mt, kc).
// lane holds A[b = mt*16+(lane&15)][k = kc*64+(lane>>4)*16+jj], jj 0..15.
// Integer compare: u < x  <=>  (bits>>9) < ceil(x*2^23)   (both exact).
// ---------------------------------------------------------------------------
__device__ __forceinline__ void spike_one(
    const float* __restrict__ x, i32x4* __restrict__ A, int t, int mt,
    int kc, int lane) {
  int b = mt * 16 + (lane & 15);
  int j0 = kc * 64 + ((lane >> 4) << 4);
  unsigned int wds[4] = {0u, 0u, 0u, 0u};
  if (j0 < 784) {                     // 784 = 49*16 (divergent only at kc=12)
    unsigned int base = (unsigned int)(t * 1024 + b) * 784u + (unsigned int)j0;
    const float* xp = x + b * 784 + j0;
#pragma unroll
    for (int q = 0; q < 4; ++q) {
      float4 xv = *(const float4*)(xp + 4 * q);
      unsigned int K0 = (unsigned int)(int)ceilf(xv.x * 8388608.0f);
      unsigned int K1 = (unsigned int)(int)ceilf(xv.y * 8388608.0f);
      unsigned int K2 = (unsigned int)(int)ceilf(xv.z * 8388608.0f);
      unsigned int K3 = (unsigned int)(int)ceilf(xv.w * 8388608.0f);
      unsigned int w4 = 0u;
      if ((tf_bits(base + 4 * q + 0) >> 9) < K0) w4 |= 1u;
      if ((tf_bits(base + 4 * q + 1) >> 9) < K1) w4 |= 1u << 8;
      if ((tf_bits(base + 4 * q + 2) >> 9) < K2) w4 |= 1u << 16;
      if ((tf_bits(base + 4 * q + 3) >> 9) < K3) w4 |= 1u << 24;
      wds[q] = w4;
    }
  }
  i32x4 v;
  v.x = (int)wds[0]; v.y = (int)wds[1]; v.z = (int)wds[2]; v.w = (int)wds[3];
  A[(size_t)((t * 64 + mt) * 13 + kc) * 64 + lane] = v;
}

// ---------------------------------------------------------------------------
// setup: one thread per WEIGHT element writes all 5 digits; spikegen for ALL
// 50 steps appended (10,400 blocks). Block 0 also zeroes the lockstep bar.
// B1 layout: [nt:64][kc:13][s:5][lane:64][jj:16]  (per-nt span contiguous).
// B2 layout: [s:5][nt:4][kc:32][lane:64][jj:16] (32x32x32).
// ---------------------------------------------------------------------------
__global__ __launch_bounds__(256) void setup_kernel(
    const float* __restrict__ W1, const float* __restrict__ W2,
    signed char* __restrict__ B1, signed char* __restrict__ B2,
    const float* __restrict__ x, i32x4* __restrict__ A,
    unsigned int* __restrict__ bar) {
  if (blockIdx.x >= PREP_BLOCKS) {
    int g = (blockIdx.x - PREP_BLOCKS) * 4 + (threadIdx.x >> 6);
    int lane = threadIdx.x & 63;
    int kc = g % 13;
    int r = g / 13;                   // t*64 + mt, t in [0,50)
    spike_one(x, A, r >> 6, r & 63, kc, lane);
    return;
  }
  if (blockIdx.x == 0 && threadIdx.x < 128) bar[threadIdx.x] = 0u;
  int idx = blockIdx.x * 256 + threadIdx.x;
  const int NB1 = 64 * 13 * 64 * 16;          // 851,968
  float w;
  signed char* dst;
  size_t stride;
  if (idx < NB1) {
    int jj = idx & 15;
    int lane = (idx >> 4) & 63;
    int kc = (idx >> 10) % 13;
    int nt = (idx >> 10) / 13;                // 0..63
    int k = kc * 64 + ((lane >> 4) << 4) + jj;
    int o = nt * 16 + (lane & 15);
    w = (o < 1000 && k < 784) ? W1[o * 784 + k] : 0.0f;
    dst = B1 + (size_t)(nt * 13 + kc) * 5120 + (lane << 4) + jj;
    stride = 1024;                            // s-stride within [kc] span
  } else {
    int m2 = idx - NB1;                       // < 131,072 (grid exact)
    int jj = m2 & 15;
    int lane = (m2 >> 4) & 63;
    int kc = (m2 >> 10) & 31;
    int nt = (m2 >> 10) >> 5;                 // 0..3
    int k = kc * 32 + ((lane >> 5) << 4) + jj;
    int o = nt * 32 + (lane & 31);
    w = (o < 100 && k < 1000) ? W2[o * 1000 + k] : 0.0f;
    dst = B2 + (size_t)(nt * 32 + kc) * 1024 + (lane << 4) + jj;
    stride = 4 * 32 * 1024;                   // s-stride (old layout)
  }
  long long V = llrint((double)w * 281474976710656.0);   // w * 2^48, exact
  signed char d = (signed char)(V & 0xFF);
  V = (V - (long long)d) >> 8;                // drop digit 0 (err <= 2^-41)
#pragma unroll
  for (int s = 0; s < 5; ++s) {
    d = (signed char)(V & 0xFF);
    V = (V - (long long)d) >> 8;
    dst[(size_t)s * stride] = d;
  }
}

// ---------------------------------------------------------------------------
// fused1 (r19 VERBATIM, FROZEN): GEMM1 + layer-1 recurrence, all 50 steps.
// 256 blocks x 512 threads (8 waves). Wave wv owns tiles (mtA, nt),
// (mtA+1, nt), mtA = (id&3)*16 + wv*2. B slice 4 register-pinned (52 VGPR);
// slices 0..3 in 53,248 B LDS, ring-2. A global ring-2. Ring slot =
// (kc + PAR) & 1 with PAR = t&1. DUAL-BANK acc: epilogue of t-1 carried at
// kc=1..8 between MFMA issues. Lockstep = block-level barrier every 10
// steps (64 arrivals, capped spin, perf hint only).
// C/D 16x16: col = lane&15, row = (lane>>4)*4 + reg.
// ---------------------------------------------------------------------------
#define F1_EPI16(CP, mi, hpp, r) do {                                         \
    double td = (double)CP[4][r];                                             \
    td = td * 256.0 + (double)CP[3][r];                                       \
    td = td * 256.0 + (double)CP[2][r];                                       \
    td = td * 256.0 + (double)CP[1][r];                                       \
    td = td * 256.0 + (double)CP[0][r];                                       \
    double I = td * 0x1p-40;                                                  \
    double mm = (((spk >> (mi)) & 1u) ? 0.0 : m[mi] * alpha) + I;             \
    m[mi] = mm;                                                               \
    unsigned int sp = ((mm - 1.0) >= 0.0) ? 1u : 0u;                          \
    spk = (spk & ~(1u << (mi))) | (sp << (mi));                               \
    hpp[(r) * 16] = (signed char)sp;                                          \
  } while (0)

// One time step. Ring slot = (kc + PAR) & 1, PAR = t & 1 (global parity;
// odd KC1 cannot flip it). Read-before-write per kc (no hazard).
#define F1_STEP(WA, WB, EA, EB, DOEPI, LAST, PAR) do {                        \
    _Pragma("unroll")                                                         \
    for (int kc = 0; kc < 13; ++kc) {                                         \
      const int sl = (kc + (PAR)) & 1;                                        \
      i32x4 avA = aA[sl], avB = aB[sl];                                       \
      if (kc + 2 < 13) {                                                      \
        aA[sl] = AtA[(kc + 2) * 64];                                          \
        aB[sl] = AtB[(kc + 2) * 64];                                          \
      } else if (!(LAST)) {                                                   \
        aA[sl] = AtA[(kc + 2 - 13) * 64 + 53248];                             \
        aB[sl] = AtB[(kc + 2 - 13) * 64 + 53248];                             \
      }                                                                       \
      i32x4 q0 = bR[sl][0], q1 = bR[sl][1],                                   \
            q2 = bR[sl][2], q3 = bR[sl][3];                                   \
      i32x4 q4 = p4[kc];                                                      \
      if (kc + 2 < 13) {                                                      \
        _Pragma("unroll")                                                     \
        for (int s = 0; s < 4; ++s)                                           \
          bR[sl][s] = blsv[((kc + 2) * 4 + s) * 64 + lane];                   \
      } else {                                                                \
        _Pragma("unroll")                                                     \
        for (int s = 0; s < 4; ++s)                                           \
          bR[sl][s] = blsv[((kc + 2 - 13) * 4 + s) * 64 + lane];              \
      }                                                                       \
      if (kc == 0) {                                                          \
        WA[0] = __builtin_amdgcn_mfma_i32_16x16x64_i8(avA, q0, Z, 0, 0, 0);   \
        WB[0] = __builtin_amdgcn_mfma_i32_16x16x64_i8(avB, q0, Z, 0, 0, 0);   \
        WA[1] = __builtin_amdgcn_mfma_i32_16x16x64_i8(avA, q1, Z, 0, 0, 0);   \
        WB[1] = __builtin_amdgcn_mfma_i32_16x16x64_i8(avB, q1, Z, 0, 0, 0);   \
        WA[2] = __builtin_amdgcn_mfma_i32_16x16x64_i8(avA, q2, Z, 0, 0, 0);   \
        WB[2] = __builtin_amdgcn_mfma_i32_16x16x64_i8(avB, q2, Z, 0, 0, 0);   \
        WA[3] = __builtin_amdgcn_mfma_i32_16x16x64_i8(avA, q3, Z, 0, 0, 0);   \
        WB[3] = __builtin_amdgcn_mfma_i32_16x16x64_i8(avB, q3, Z, 0, 0, 0);   \
        WA[4] = __builtin_amdgcn_mfma_i32_16x16x64_i8(avA, q4, Z, 0, 0, 0);   \
        WB[4] = __builtin_amdgcn_mfma_i32_16x16x64_i8(avB, q4, Z, 0, 0, 0);   \
      } else {                                                                \
        WA[0] = __builtin_amdgcn_mfma_i32_16x16x64_i8(avA, q0, WA[0], 0,0,0); \
        WB[0] = __builtin_amdgcn_mfma_i32_16x16x64_i8(avB, q0, WB[0], 0,0,0); \
        WA[1] = __builtin_amdgcn_mfma_i32_16x16x64_i8(avA, q1, WA[1], 0,0,0); \
        WB[1] = __builtin_amdgcn_mfma_i32_16x16x64_i8(avB, q1, WB[1], 0,0,0); \
        WA[2] = __builtin_amdgcn_mfma_i32_16x16x64_i8(avA, q2, WA[2], 0,0,0); \
        WB[2] = __builtin_amdgcn_mfma_i32_16x16x64_i8(avB, q2, WB[2], 0,0,0); \
        WA[3] = __builtin_amdgcn_mfma_i32_16x16x64_i8(avA, q3, WA[3], 0,0,0); \
        WB[3] = __builtin_amdgcn_mfma_i32_16x16x64_i8(avB, q3, WB[3], 0,0,0); \
        WA[4] = __builtin_amdgcn_mfma_i32_16x16x64_i8(avA, q4, WA[4], 0,0,0); \
        WB[4] = __builtin_amdgcn_mfma_i32_16x16x64_i8(avB, q4, WB[4], 0,0,0); \
      }                                                                       \
      if ((DOEPI) && kc >= 1 && kc <= 4) F1_EPI16(EA, kc - 1, hpA, kc - 1);   \
      if ((DOEPI) && kc >= 5 && kc <= 8) F1_EPI16(EB, kc - 1, hpB, kc - 5);   \
    }                                                                         \
    if (DOEPI) { hpA += 1048576; hpB += 1048576; }                            \
    if (!(LAST)) { AtA += 53248; AtB += 53248; }                              \
  } while (0)

__global__ __launch_bounds__(512, 1) void fused1_kernel(
    const signed char* __restrict__ B1, const i32x4* __restrict__ Afc,
    signed char* __restrict__ h1sc, const float* __restrict__ tau0,
    unsigned int* __restrict__ bar) {
  extern __shared__ i32x4 blsv[];             // [13 kc][4 sl][64] = 53,248 B
  const int tid = threadIdx.x, lane = tid & 63, wv = tid >> 6;  // wv 0..7
  const int id = (int)blockIdx.x;
  const int mtg = id & 3, nt = id >> 2;       // XCD pins mtg (A-locality)
  const int mtA = mtg * 16 + wv * 2;          // m-tiles mtA, mtA+1
  const i32x4* B1v = (const i32x4*)B1;

  // one-time B pin (slices 0..3) -> LDS (3328 i32x4)
  for (int r = tid; r < 3328; r += 512) {
    int kc = r >> 8;                          // r / 256
    int rem = r & 255;                        // s*64 + lane, s in 0..3
    blsv[r] = B1v[(size_t)nt * 4160 + (size_t)kc * 320 + rem];
  }

  // register-pinned B slice 4 (time-invariant): 13 x b128 = 52 VGPR
  i32x4 p4[13];
#pragma unroll
  for (int kc = 0; kc < 13; ++kc)
    p4[kc] = B1v[(size_t)nt * 4160 + (size_t)kc * 320 + 4 * 64 + lane];

  const double alpha = 1.0 / (1.0 + exp(-(double)tau0[0]));
  double m[8];                                // rows: [0..3]=tileA, [4..7]=B
  unsigned int spk = 0;
#pragma unroll
  for (int r = 0; r < 8; ++r) m[r] = 0.5;

  i32x4 Z;                                    // hoisted zero C-in for kc==0
  Z.x = 0; Z.y = 0; Z.z = 0; Z.w = 0;
  i32x4 Ca[5], Cb[5];                         // bank 0 (tiles A,B)
  i32x4 Da[5], Db[5];                         // bank 1 (tiles A,B)

  const i32x4* AtA = Afc + (size_t)(mtA * 13) * 64 + lane;     // t+=53,248
  const i32x4* AtB = AtA + 13 * 64;
  // h1sc[t][o16=nt][b][o_lo]: wave writes rows b = mtA*16 + (lane>>4)*4 + r
  signed char* hpA = h1sc
      + ((size_t)(nt) * 1024 + mtA * 16 + ((lane >> 4) << 2)) * 16
      + (lane & 15);
  signed char* hpB = hpA + 16 * 16;           // +16 rows

  // prologue A ring (t=0: slot0=kc0, slot1=kc1) -- pre-barrier
  i32x4 aA[2], aB[2];
  aA[0] = AtA[0]; aA[1] = AtA[64];
  aB[0] = AtB[0]; aB[1] = AtB[64];

  __syncthreads();                            // LDS pin complete (only bar)

  // prologue LDS ring (t=0: slot0=kc0, slot1=kc1; slices 0..3)
  i32x4 bR[2][4];
#pragma unroll
  for (int kc = 0; kc < 2; ++kc)
#pragma unroll
    for (int s = 0; s < 4; ++s)
      bR[kc][s] = blsv[(kc * 4 + s) * 64 + lane];

  // t = 0 (PAR 0): fill bank 0, no epilogue
  F1_STEP(Ca, Cb, Da, Db, 0, 0, 0);
  // t = 1..48 in pairs: write bank(t&1), epilogue bank((t-1)&1)
#pragma unroll 1
  for (int tp = 0; tp < 24; ++tp) {
    F1_STEP(Da, Db, Ca, Cb, 1, 0, 1);         // odd t (PAR 1): epi bank0
    F1_STEP(Ca, Cb, Da, Db, 1, 0, 0);         // even t (PAR 0): epi bank1
    if (((tp + 1) % 5) == 0) {
      __syncthreads();
      if (tid == 0) {
        int ph = (tp + 1) / 5 - 1;            // 0..3
        unsigned int* c = bar + (mtg << 4) + ph;
        __hip_atomic_fetch_add(c, 1u, __ATOMIC_RELAXED,
                               __HIP_MEMORY_SCOPE_AGENT);
        for (int spin = 0; spin < 20000; ++spin) {
          if (__hip_atomic_load(c, __ATOMIC_RELAXED,
                                __HIP_MEMORY_SCOPE_AGENT) >= 64u) break;
          __builtin_amdgcn_s_sleep(2);
        }
      }
      __syncthreads();
    }
  }
  F1_STEP(Da, Db, Ca, Cb, 1, 1, 1);           // t = 49 (PAR 1; no A advance)
  // final epilogue for t = 49 (bank 1)
#pragma unroll
  for (int r = 0; r < 4; ++r) F1_EPI16(Da, r, hpA, r);
#pragma unroll
  for (int r = 0; r < 4; ++r) F1_EPI16(Db, r + 4, hpB, r);
}

// ---------------------------------------------------------------------------
// GEMM2 (r24 decode + 4-kc phases): M=50*1024, N=128, K=1024, 5 slices
// (32x32x32). Decode q=id&7, nt=(id>>3)&3, tl=id>>5 (XCD co-location).
// bls[2][4][5][64] (40,960B, 3 blocks/CU): phase p computes kc 4p..4p+3
// from buf p&1; writes buf (p+1)&1 from regs staged 2 phases earlier;
// issues loads for phase p+2; ONE barrier per phase (9 total vs 32).
// A = h1sc [t][o16][b][o_lo] (16B/lane coalesced), rolling ring.
// Output = EXACT int48 split planes (i32 low + i16 high; |T| < 2^47).
// ---------------------------------------------------------------------------
__global__ __launch_bounds__(256, 3) void gemm2_kernel(
    const signed char* __restrict__ Bf, const signed char* __restrict__ h1sc,
    int* __restrict__ T2L, short* __restrict__ T2H) {
  __shared__ i32x4 bls[2][4][NSL][64];        // 40,960 B
  int tid = threadIdx.x, lane = tid & 63, wv = tid >> 6;
  int id = (int)blockIdx.x;
  int q  = id & 7;                     // XCD pin (id%8 = q for all nt)
  int nt = (id >> 3) & 3;              // 0..3
  int tl = id >> 5;                    // 0..49
  int mt = (q << 2) + wv;              // 0..31
  const i32x4* Ar = (const i32x4*)h1sc
      + ((size_t)tl * 64 + (lane >> 5)) * 1024 + mt * 32 + (lane & 31);
  const i32x4* Bp = (const i32x4*)Bf + lane;
  const bool st4 = (wv == 0);
#define B2_IDX(s, kc) ((size_t)(((s) * 4 + nt) * 32 + (kc)) * 64)

  i32x16 C[NSL];
#pragma unroll
  for (int s = 0; s < NSL; ++s)
#pragma unroll
    for (int i = 0; i < 16; ++i) C[s][i] = 0;

  // prologue: buffer 0 = kc 0..3 (direct); stage regs = kc 4..7 (buf 1)
#pragma unroll
  for (int k = 0; k < 4; ++k) {
    bls[0][k][wv][lane] = Bp[B2_IDX(wv, k)];
    if (st4) bls[0][k][4][lane] = Bp[B2_IDX(4, k)];
  }
  i32x4 s0 = Bp[B2_IDX(wv, 4)], s1 = Bp[B2_IDX(wv, 5)],
        s2 = Bp[B2_IDX(wv, 6)], s3 = Bp[B2_IDX(wv, 7)];
  i32x4 u0, u1, u2, u3;
  if (st4) { u0 = Bp[B2_IDX(4, 4)]; u1 = Bp[B2_IDX(4, 5)];
             u2 = Bp[B2_IDX(4, 6)]; u3 = Bp[B2_IDX(4, 7)]; }
  i32x4 a0 = Ar[0];
  i32x4 a1 = Ar[2048];
  i32x4 a2;
  __syncthreads();                     // buf0 ready

#pragma unroll 1
  for (int p = 0; p < 8; ++p) {
    const int cur = p & 1, nxt = cur ^ 1;
    if (p + 1 < 8) {                   // write buf (p+1)&1 (readers of this
      bls[nxt][0][wv][lane] = s0;      //  buffer finished at the p-1 barrier)
      bls[nxt][1][wv][lane] = s1;
      bls[nxt][2][wv][lane] = s2;
      bls[nxt][3][wv][lane] = s3;
      if (st4) {
        bls[nxt][0][4][lane] = u0; bls[nxt][1][4][lane] = u1;
        bls[nxt][2][4][lane] = u2; bls[nxt][3][4][lane] = u3;
      }
    }
    if (p + 2 < 8) {                   // issue loads for phase p+2
      int kb = 4 * (p + 2);
      s0 = Bp[B2_IDX(wv, kb + 0)]; s1 = Bp[B2_IDX(wv, kb + 1)];
      s2 = Bp[B2_IDX(wv, kb + 2)]; s3 = Bp[B2_IDX(wv, kb + 3)];
      if (st4) {
        u0 = Bp[B2_IDX(4, kb + 0)]; u1 = Bp[B2_IDX(4, kb + 1)];
        u2 = Bp[B2_IDX(4, kb + 2)]; u3 = Bp[B2_IDX(4, kb + 3)];
      }
    }
#pragma unroll
    for (int k = 0; k < 4; ++k) {
      const int kc = 4 * p + k;
      i32x4 b0 = bls[cur][k][0][lane], b1 = bls[cur][k][1][lane],
            b2 = bls[cur][k][2][lane], b3 = bls[cur][k][3][lane],
            b4 = bls[cur][k][4][lane];
      if (kc + 2 < 32) a2 = Ar[(size_t)(kc + 2) * 2048];
      C[0] = __builtin_amdgcn_mfma_i32_32x32x32_i8(a0, b0, C[0], 0, 0, 0);
      C[1] = __builtin_amdgcn_mfma_i32_32x32x32_i8(a0, b1, C[1], 0, 0, 0);
      C[2] = __builtin_amdgcn_mfma_i32_32x32x32_i8(a0, b2, C[2], 0, 0, 0);
      C[3] = __builtin_amdgcn_mfma_i32_32x32x32_i8(a0, b3, C[3], 0, 0, 0);
      C[4] = __builtin_amdgcn_mfma_i32_32x32x32_i8(a0, b4, C[4], 0, 0, 0);
      a0 = a1; a1 = a2;
    }
    __syncthreads();                   // buf cur consumed; writes visible
  }

  int o = nt * 32 + (lane & 31);
  int rb = 4 * (lane >> 5);
#pragma unroll
  for (int r = 0; r < 16; ++r) {
    int row = (r & 3) + 8 * (r >> 2) + rb;
    int b = mt * 32 + row;
    long long T = (long long)C[4][r];
    T = (T << 8) + (long long)C[3][r];
    T = (T << 8) + (long long)C[2][r];
    T = (T << 8) + (long long)C[1][r];
    T = (T << 8) + (long long)C[0][r];
    size_t i0 = ((size_t)tl * 1024 + b) * 128 + o;
    T2L[i0] = (int)T;
    T2H[i0] = (short)(T >> 32);
  }
}

// ---------------------------------------------------------------------------
// rec2: layer-2 membrane recurrence + AvgPool(10) + pPLI accumulator.
// T = (Th<<32) + (u32)Tl reconstruct (exact int48); next-step planes
// prefetched before the current update (LLC latency off the serial chain).
// ---------------------------------------------------------------------------
__global__ __launch_bounds__(256) void rec2_kernel(
    const int* __restrict__ T2L, const short* __restrict__ T2H,
    double* __restrict__ h2m_st,
    signed char* __restrict__ h2s_st, double* __restrict__ acc_st,
    const float* __restrict__ tauv, const float* __restrict__ acct,
    float* __restrict__ out) {
  __shared__ signed char sp[256];
  int tid = threadIdx.x;
  int b = blockIdx.x * 2 + (tid >> 7);
  int o = tid & 127;
  double alpha = 1.0 / (1.0 + exp(-(double)tauv[0]));
  double adec  = 1.0 / (1.0 + exp(-(double)acct[0]));
  double m = 0.5, s = 0.0, accv = 0.0;
  bool isPool = (o < 10);
  const int*   Lp = T2L + (size_t)b * 128 + o;   // + tl*131072 per step
  const short* Hp = T2H + (size_t)b * 128 + o;
  int   Tl = Lp[0];
  short Th = Hp[0];
  for (int tl = 0; tl < NSTEPS; ++tl) {
    int Tl2 = 0; short Th2 = 0;
    if (tl + 1 < NSTEPS) {                   // prefetch next step's planes
      Tl2 = Lp[(size_t)(tl + 1) * 131072];
      Th2 = Hp[(size_t)(tl + 1) * 131072];
    }
    long long T = ((long long)Th << 32) + (long long)(unsigned int)Tl;
    double I = (double)T * 0x1p-40;
    m = (s != 0.0 ? 0.0 : m * alpha) + I;
    bool spkb = (m - 1.0) >= 0.0;
    s = spkb ? 1.0 : 0.0;
    sp[tid] = spkb ? 1 : 0;
    __syncthreads();
    if (isPool) {
      int base = tid & 128;
      int isum = 0;
#pragma unroll
      for (int k = 0; k < 10; ++k) isum += sp[base + o * 10 + k];
      accv = accv * adec + (double)isum / 10.0;
      if (tl == NSTEPS - 1) out[b * 10 + o] = (float)accv;
    }
    __syncthreads();
    Tl = Tl2; Th = Th2;
  }
  h2m_st[(size_t)b * 128 + o] = m;
  h2s_st[(size_t)b * 128 + o] = (signed char)(s != 0.0 ? 1 : 0);
  if (isPool) acc_st[b * 10 + o] = accv;
}

// ---------------------------------------------------------------------------
extern "C" void kernel_launch(void* const* d_in, const int* in_sizes, int n_in,
                              void* d_out, int out_size, void* d_ws, size_t ws_size,
                              hipStream_t stream) {
  const float* x    = (const float*)d_in[0];
  const float* W1   = (const float*)d_in[1];
  const float* W2   = (const float*)d_in[2];
  const float* tau0 = (const float*)d_in[3];
  const float* tauv = (const float*)d_in[4];
  const float* acct = (const float*)d_in[5];
  float* out = (float*)d_out;
  char*  ws  = (char*)d_ws;

  signed char* B1     = (signed char*)(ws + OFF_B1);
  signed char* B2     = (signed char*)(ws + OFF_B2);
  signed char* Af     = (signed char*)(ws + OFF_AF);
  signed char* h1sc   = (signed char*)(ws + OFF_H1SC);
  int*         T2L    = (int*)(ws + OFF_T2L);
  short*       T2H    = (short*)(ws + OFF_T2H);
  double*      h2m_st = (double*)(ws + OFF_H2M);
  signed char* h2s_st = (signed char*)(ws + OFF_H2S);
  double*      acc_st = (double*)(ws + OFF_ACC);
  unsigned int* bar   = (unsigned int*)(ws + OFF_BAR);
  i32x4*       Afv    = (i32x4*)Af;

  // dynamic LDS for fused1 (53,248 B; attribute kept for safety)
  static bool attr_done = false;
  if (!attr_done) {
    (void)hipFuncSetAttribute((const void*)fused1_kernel,
                              hipFuncAttributeMaxDynamicSharedMemorySize,
                              53248);
    attr_done = true;
  }

  // 1) weight digit prep (3840 blocks) + spikegen for ALL 50 steps (10,400)
  setup_kernel<<<PREP_BLOCKS + SPK_BLOCKS, 256, 0, stream>>>(
      W1, W2, B1, B2, x, Afv, bar);

  // 2) time-fused layer 1: all 50 steps, membranes register-resident
  fused1_kernel<<<256, 512, 53248, stream>>>(B1, Afv, h1sc, tau0, bar);

  // 3) layer 2 GEMM over all 50 steps (XCD-swizzled, 4-kc phases, 9 bars)
  gemm2_kernel<<<4 * NSTEPS * 8, 256, 0, stream>>>(B2, h1sc, T2L, T2H);

  // 4) layer 2 recurrence + pooling + accumulator (prefetched planes)
  rec2_kernel<<<512, 256, 0, stream>>>(
      T2L, T2H, h2m_st, h2s_st, acc_st, tauv, acct, out);
}

// Round 18
// 390.103 us; speedup vs baseline: 1.0231x; 1.0231x over previous
//
#include <hip/hip_runtime.h>
#include <hip/hip_bf16.h>
#include <math.h>

// ---------------------------------------------------------------------------
// sMLP4 round 27: FINAL REVERT to best-measured configuration (r24, 390.5us).
// r26 post-mortem: 4-kc phases (32->9 barriers) = 399us, slightly WORSE =>
// barrier-drain theory falsified. gemm2 is 4-for-4 nulled mechanisms
// (barrier-free r22 / XCD swizzle r24 (+12) / triple-buffer r25 (null) /
// phase-split r26 (null)); its residual ~85us is below the granularity of
// single-change levers (most plausibly dispatch/drain behavior at 1600
// short blocks). Pipeline state:
//   fused1 FROZEN at r19 (211us, 45% MfmaUtil; 5 edits all regressed at
//          the unified-register ceiling);
//   setup  ~45us (threefry VALU floor ~28);
//   gemm2  r24 text (best-measured variant);
//   rec2   ~25us (86MB stream floor ~15).
// This round: gemm2 reverted to r24 verbatim; everything else unchanged.
// Trajectory bit-identical to rounds 10-26 (absmax 0.0009765625).
// ---------------------------------------------------------------------------

#define NSTEPS 50
#define KC1 13                     // K chunks of 64 for layer 1 (832 >= 784)
#define NSL 5                      // digit slices (digits 1..5 of 2^48 fix-pt)

typedef __attribute__((ext_vector_type(4)))  int i32x4;
typedef __attribute__((ext_vector_type(16))) int i32x16;

// fixed workspace layout (bytes, all 256-aligned)
#define OFF_B1     0ull            // i8 [64*13*5*64*16] = 4,259,840
#define OFF_B2     4259840ull      // i8 [5*4*32*1024]   =   655,360
#define OFF_AF     4915200ull      // i8 [50*64*13*64*16]= 42,598,400
#define OFF_H1SC   47513600ull     // i8 [50*64*1024*16] = 52,428,800
#define OFF_T2L    99942400ull     // i32[50*1024*128]   = 26,214,400
#define OFF_T2H    126156800ull    // i16[50*1024*128]   = 13,107,200
#define OFF_H2M    139264000ull    // f64[1024*128]      = 1,048,576
#define OFF_H2S    140312576ull    // i8 [1024*128]      =   131,072
#define OFF_ACC    140443648ull    // f64[1024*10]       =    81,920
#define OFF_BAR    140525568ull    // u32[128] lockstep counters (512 B)
#define WS_END     140526080ull    // 134 MB

#define PREP_BLOCKS 3840           // (851,968 + 131,072) / 256
#define SPK_BLOCKS 10400           // 50*64*13 groups / 4

// ---------------------------------------------------------------------------
// threefry2x32, key (0,42), partitionable mode: bits(i) = x0^x1 on ctr (0,i)
// ---------------------------------------------------------------------------
__device__ __forceinline__ unsigned int rotl32(unsigned int v, int d) {
#if __has_builtin(__builtin_amdgcn_alignbit)
  return __builtin_amdgcn_alignbit(v, v, (unsigned int)(32 - d));
#else
  return (v << d) | (v >> (32 - d));
#endif
}

__device__ __forceinline__ unsigned int tf_bits(unsigned int i) {
  const unsigned int ks0 = 0u;
  const unsigned int ks1 = 42u;
  const unsigned int ks2 = 0x1BD11BDAu ^ 0u ^ 42u;
  unsigned int x0 = 0u + ks0;
  unsigned int x1 = i + ks1;
#define TF_RND(r) { x0 += x1; x1 = rotl32(x1, r); x1 ^= x0; }
  TF_RND(13) TF_RND(15) TF_RND(26) TF_RND(6)
  x0 += ks1; x1 += ks2 + 1u;
  TF_RND(17) TF_RND(29) TF_RND(16) TF_RND(24)
  x0 += ks2; x1 += ks0 + 2u;
  TF_RND(13) TF_RND(15) TF_RND(26) TF_RND(6)
  x0 += ks0; x1 += ks1 + 3u;
  TF_RND(17) TF_RND(29) TF_RND(16) TF_RND(24)
  x0 += ks1; x1 += ks2 + 4u;
  TF_RND(13) TF_RND(15) TF_RND(26) TF_RND(6)
  x0 += ks2; x1 += ks0 + 5u;
#undef TF_RND
  return x0 ^ x1;
}

// ---------------------------------------------------------------------------
// one spikegen group: A-frag (16x16x64) for (t, mt, kc).
// lane holds A[b = mt*16+(lane&15)][k = kc*64+(lane>>4)*16+jj], jj 0..15.
// Integer compare: u < x  <=>  (bits>>9) < ceil(x*2^23)   (both exact).
// ---------------------------------------------------------------------------
__device__ __forceinline__ void spike_one(
    const float* __restrict__ x, i32x4* __restrict__ A, int t, int mt,
    int kc, int lane) {
  int b = mt * 16 + (lane & 15);
  int j0 = kc * 64 + ((lane >> 4) << 4);
  unsigned int wds[4] = {0u, 0u, 0u, 0u};
  if (j0 < 784) {                     // 784 = 49*16 (divergent only at kc=12)
    unsigned int base = (unsigned int)(t * 1024 + b) * 784u + (unsigned int)j0;
    const float* xp = x + b * 784 + j0;
#pragma unroll
    for (int q = 0; q < 4; ++q) {
      float4 xv = *(const float4*)(xp + 4 * q);
      unsigned int K0 = (unsigned int)(int)ceilf(xv.x * 8388608.0f);
      unsigned int K1 = (unsigned int)(int)ceilf(xv.y * 8388608.0f);
      unsigned int K2 = (unsigned int)(int)ceilf(xv.z * 8388608.0f);
      unsigned int K3 = (unsigned int)(int)ceilf(xv.w * 8388608.0f);
      unsigned int w4 = 0u;
      if ((tf_bits(base + 4 * q + 0) >> 9) < K0) w4 |= 1u;
      if ((tf_bits(base + 4 * q + 1) >> 9) < K1) w4 |= 1u << 8;
      if ((tf_bits(base + 4 * q + 2) >> 9) < K2) w4 |= 1u << 16;
      if ((tf_bits(base + 4 * q + 3) >> 9) < K3) w4 |= 1u << 24;
      wds[q] = w4;
    }
  }
  i32x4 v;
  v.x = (int)wds[0]; v.y = (int)wds[1]; v.z = (int)wds[2]; v.w = (int)wds[3];
  A[(size_t)((t * 64 + mt) * 13 + kc) * 64 + lane] = v;
}

// ---------------------------------------------------------------------------
// setup: one thread per WEIGHT element writes all 5 digits; spikegen for ALL
// 50 steps appended (10,400 blocks). Block 0 also zeroes the lockstep bar.
// B1 layout: [nt:64][kc:13][s:5][lane:64][jj:16]  (per-nt span contiguous).
// B2 layout: [s:5][nt:4][kc:32][lane:64][jj:16] (32x32x32).
// ---------------------------------------------------------------------------
__global__ __launch_bounds__(256) void setup_kernel(
    const float* __restrict__ W1, const float* __restrict__ W2,
    signed char* __restrict__ B1, signed char* __restrict__ B2,
    const float* __restrict__ x, i32x4* __restrict__ A,
    unsigned int* __restrict__ bar) {
  if (blockIdx.x >= PREP_BLOCKS) {
    int g = (blockIdx.x - PREP_BLOCKS) * 4 + (threadIdx.x >> 6);
    int lane = threadIdx.x & 63;
    int kc = g % 13;
    int r = g / 13;                   // t*64 + mt, t in [0,50)
    spike_one(x, A, r >> 6, r & 63, kc, lane);
    return;
  }
  if (blockIdx.x == 0 && threadIdx.x < 128) bar[threadIdx.x] = 0u;
  int idx = blockIdx.x * 256 + threadIdx.x;
  const int NB1 = 64 * 13 * 64 * 16;          // 851,968
  float w;
  signed char* dst;
  size_t stride;
  if (idx < NB1) {
    int jj = idx & 15;
    int lane = (idx >> 4) & 63;
    int kc = (idx >> 10) % 13;
    int nt = (idx >> 10) / 13;                // 0..63
    int k = kc * 64 + ((lane >> 4) << 4) + jj;
    int o = nt * 16 + (lane & 15);
    w = (o < 1000 && k < 784) ? W1[o * 784 + k] : 0.0f;
    dst = B1 + (size_t)(nt * 13 + kc) * 5120 + (lane << 4) + jj;
    stride = 1024;                            // s-stride within [kc] span
  } else {
    int m2 = idx - NB1;                       // < 131,072 (grid exact)
    int jj = m2 & 15;
    int lane = (m2 >> 4) & 63;
    int kc = (m2 >> 10) & 31;
    int nt = (m2 >> 10) >> 5;                 // 0..3
    int k = kc * 32 + ((lane >> 5) << 4) + jj;
    int o = nt * 32 + (lane & 31);
    w = (o < 100 && k < 1000) ? W2[o * 1000 + k] : 0.0f;
    dst = B2 + (size_t)(nt * 32 + kc) * 1024 + (lane << 4) + jj;
    stride = 4 * 32 * 1024;                   // s-stride (old layout)
  }
  long long V = llrint((double)w * 281474976710656.0);   // w * 2^48, exact
  signed char d = (signed char)(V & 0xFF);
  V = (V - (long long)d) >> 8;                // drop digit 0 (err <= 2^-41)
#pragma unroll
  for (int s = 0; s < 5; ++s) {
    d = (signed char)(V & 0xFF);
    V = (V - (long long)d) >> 8;
    dst[(size_t)s * stride] = d;
  }
}

// ---------------------------------------------------------------------------
// fused1 (r19 VERBATIM, FROZEN): GEMM1 + layer-1 recurrence, all 50 steps.
// 256 blocks x 512 threads (8 waves). Wave wv owns tiles (mtA, nt),
// (mtA+1, nt), mtA = (id&3)*16 + wv*2. B slice 4 register-pinned (52 VGPR);
// slices 0..3 in 53,248 B LDS, ring-2. A global ring-2. Ring slot =
// (kc + PAR) & 1 with PAR = t&1. DUAL-BANK acc: epilogue of t-1 carried at
// kc=1..8 between MFMA issues. Lockstep = block-level barrier every 10
// steps (64 arrivals, capped spin, perf hint only).
// C/D 16x16: col = lane&15, row = (lane>>4)*4 + reg.
// ---------------------------------------------------------------------------
#define F1_EPI16(CP, mi, hpp, r) do {                                         \
    double td = (double)CP[4][r];                                             \
    td = td * 256.0 + (double)CP[3][r];                                       \
    td = td * 256.0 + (double)CP[2][r];                                       \
    td = td * 256.0 + (double)CP[1][r];                                       \
    td = td * 256.0 + (double)CP[0][r];                                       \
    double I = td * 0x1p-40;                                                  \
    double mm = (((spk >> (mi)) & 1u) ? 0.0 : m[mi] * alpha) + I;             \
    m[mi] = mm;                                                               \
    unsigned int sp = ((mm - 1.0) >= 0.0) ? 1u : 0u;                          \
    spk = (spk & ~(1u << (mi))) | (sp << (mi));                               \
    hpp[(r) * 16] = (signed char)sp;                                          \
  } while (0)

// One time step. Ring slot = (kc + PAR) & 1, PAR = t & 1 (global parity;
// odd KC1 cannot flip it). Read-before-write per kc (no hazard).
#define F1_STEP(WA, WB, EA, EB, DOEPI, LAST, PAR) do {                        \
    _Pragma("unroll")                                                         \
    for (int kc = 0; kc < 13; ++kc) {                                         \
      const int sl = (kc + (PAR)) & 1;                                        \
      i32x4 avA = aA[sl], avB = aB[sl];                                       \
      if (kc + 2 < 13) {                                                      \
        aA[sl] = AtA[(kc + 2) * 64];                                          \
        aB[sl] = AtB[(kc + 2) * 64];                                          \
      } else if (!(LAST)) {                                                   \
        aA[sl] = AtA[(kc + 2 - 13) * 64 + 53248];                             \
        aB[sl] = AtB[(kc + 2 - 13) * 64 + 53248];                             \
      }                                                                       \
      i32x4 q0 = bR[sl][0], q1 = bR[sl][1],                                   \
            q2 = bR[sl][2], q3 = bR[sl][3];                                   \
      i32x4 q4 = p4[kc];                                                      \
      if (kc + 2 < 13) {                                                      \
        _Pragma("unroll")                                                     \
        for (int s = 0; s < 4; ++s)                                           \
          bR[sl][s] = blsv[((kc + 2) * 4 + s) * 64 + lane];                   \
      } else {                                                                \
        _Pragma("unroll")                                                     \
        for (int s = 0; s < 4; ++s)                                           \
          bR[sl][s] = blsv[((kc + 2 - 13) * 4 + s) * 64 + lane];              \
      }                                                                       \
      if (kc == 0) {                                                          \
        WA[0] = __builtin_amdgcn_mfma_i32_16x16x64_i8(avA, q0, Z, 0, 0, 0);   \
        WB[0] = __builtin_amdgcn_mfma_i32_16x16x64_i8(avB, q0, Z, 0, 0, 0);   \
        WA[1] = __builtin_amdgcn_mfma_i32_16x16x64_i8(avA, q1, Z, 0, 0, 0);   \
        WB[1] = __builtin_amdgcn_mfma_i32_16x16x64_i8(avB, q1, Z, 0, 0, 0);   \
        WA[2] = __builtin_amdgcn_mfma_i32_16x16x64_i8(avA, q2, Z, 0, 0, 0);   \
        WB[2] = __builtin_amdgcn_mfma_i32_16x16x64_i8(avB, q2, Z, 0, 0, 0);   \
        WA[3] = __builtin_amdgcn_mfma_i32_16x16x64_i8(avA, q3, Z, 0, 0, 0);   \
        WB[3] = __builtin_amdgcn_mfma_i32_16x16x64_i8(avB, q3, Z, 0, 0, 0);   \
        WA[4] = __builtin_amdgcn_mfma_i32_16x16x64_i8(avA, q4, Z, 0, 0, 0);   \
        WB[4] = __builtin_amdgcn_mfma_i32_16x16x64_i8(avB, q4, Z, 0, 0, 0);   \
      } else {                                                                \
        WA[0] = __builtin_amdgcn_mfma_i32_16x16x64_i8(avA, q0, WA[0], 0,0,0); \
        WB[0] = __builtin_amdgcn_mfma_i32_16x16x64_i8(avB, q0, WB[0], 0,0,0); \
        WA[1] = __builtin_amdgcn_mfma_i32_16x16x64_i8(avA, q1, WA[1], 0,0,0); \
        WB[1] = __builtin_amdgcn_mfma_i32_16x16x64_i8(avB, q1, WB[1], 0,0,0); \
        WA[2] = __builtin_amdgcn_mfma_i32_16x16x64_i8(avA, q2, WA[2], 0,0,0); \
        WB[2] = __builtin_amdgcn_mfma_i32_16x16x64_i8(avB, q2, WB[2], 0,0,0); \
        WA[3] = __builtin_amdgcn_mfma_i32_16x16x64_i8(avA, q3, WA[3], 0,0,0); \
        WB[3] = __builtin_amdgcn_mfma_i32_16x16x64_i8(avB, q3, WB[3], 0,0,0); \
        WA[4] = __builtin_amdgcn_mfma_i32_16x16x64_i8(avA, q4, WA[4], 0,0,0); \
        WB[4] = __builtin_amdgcn_mfma_i32_16x16x64_i8(avB, q4, WB[4], 0,0,0); \
      }                                                                       \
      if ((DOEPI) && kc >= 1 && kc <= 4) F1_EPI16(EA, kc - 1, hpA, kc - 1);   \
      if ((DOEPI) && kc >= 5 && kc <= 8) F1_EPI16(EB, kc - 1, hpB, kc - 5);   \
    }                                                                         \
    if (DOEPI) { hpA += 1048576; hpB += 1048576; }                            \
    if (!(LAST)) { AtA += 53248; AtB += 53248; }                              \
  } while (0)

__global__ __launch_bounds__(512, 1) void fused1_kernel(
    const signed char* __restrict__ B1, const i32x4* __restrict__ Afc,
    signed char* __restrict__ h1sc, const float* __restrict__ tau0,
    unsigned int* __restrict__ bar) {
  extern __shared__ i32x4 blsv[];             // [13 kc][4 sl][64] = 53,248 B
  const int tid = threadIdx.x, lane = tid & 63, wv = tid >> 6;  // wv 0..7
  const int id = (int)blockIdx.x;
  const int mtg = id & 3, nt = id >> 2;       // XCD pins mtg (A-locality)
  const int mtA = mtg * 16 + wv * 2;          // m-tiles mtA, mtA+1
  const i32x4* B1v = (const i32x4*)B1;

  // one-time B pin (slices 0..3) -> LDS (3328 i32x4)
  for (int r = tid; r < 3328; r += 512) {
    int kc = r >> 8;                          // r / 256
    int rem = r & 255;                        // s*64 + lane, s in 0..3
    blsv[r] = B1v[(size_t)nt * 4160 + (size_t)kc * 320 + rem];
  }

  // register-pinned B slice 4 (time-invariant): 13 x b128 = 52 VGPR
  i32x4 p4[13];
#pragma unroll
  for (int kc = 0; kc < 13; ++kc)
    p4[kc] = B1v[(size_t)nt * 4160 + (size_t)kc * 320 + 4 * 64 + lane];

  const double alpha = 1.0 / (1.0 + exp(-(double)tau0[0]));
  double m[8];                                // rows: [0..3]=tileA, [4..7]=B
  unsigned int spk = 0;
#pragma unroll
  for (int r = 0; r < 8; ++r) m[r] = 0.5;

  i32x4 Z;                                    // hoisted zero C-in for kc==0
  Z.x = 0; Z.y = 0; Z.z = 0; Z.w = 0;
  i32x4 Ca[5], Cb[5];                         // bank 0 (tiles A,B)
  i32x4 Da[5], Db[5];                         // bank 1 (tiles A,B)

  const i32x4* AtA = Afc + (size_t)(mtA * 13) * 64 + lane;     // t+=53,248
  const i32x4* AtB = AtA + 13 * 64;
  // h1sc[t][o16=nt][b][o_lo]: wave writes rows b = mtA*16 + (lane>>4)*4 + r
  signed char* hpA = h1sc
      + ((size_t)(nt) * 1024 + mtA * 16 + ((lane >> 4) << 2)) * 16
      + (lane & 15);
  signed char* hpB = hpA + 16 * 16;           // +16 rows

  // prologue A ring (t=0: slot0=kc0, slot1=kc1) -- pre-barrier
  i32x4 aA[2], aB[2];
  aA[0] = AtA[0]; aA[1] = AtA[64];
  aB[0] = AtB[0]; aB[1] = AtB[64];

  __syncthreads();                            // LDS pin complete (only bar)

  // prologue LDS ring (t=0: slot0=kc0, slot1=kc1; slices 0..3)
  i32x4 bR[2][4];
#pragma unroll
  for (int kc = 0; kc < 2; ++kc)
#pragma unroll
    for (int s = 0; s < 4; ++s)
      bR[kc][s] = blsv[(kc * 4 + s) * 64 + lane];

  // t = 0 (PAR 0): fill bank 0, no epilogue
  F1_STEP(Ca, Cb, Da, Db, 0, 0, 0);
  // t = 1..48 in pairs: write bank(t&1), epilogue bank((t-1)&1)
#pragma unroll 1
  for (int tp = 0; tp < 24; ++tp) {
    F1_STEP(Da, Db, Ca, Cb, 1, 0, 1);         // odd t (PAR 1): epi bank0
    F1_STEP(Ca, Cb, Da, Db, 1, 0, 0);         // even t (PAR 0): epi bank1
    if (((tp + 1) % 5) == 0) {
      __syncthreads();
      if (tid == 0) {
        int ph = (tp + 1) / 5 - 1;            // 0..3
        unsigned int* c = bar + (mtg << 4) + ph;
        __hip_atomic_fetch_add(c, 1u, __ATOMIC_RELAXED,
                               __HIP_MEMORY_SCOPE_AGENT);
        for (int spin = 0; spin < 20000; ++spin) {
          if (__hip_atomic_load(c, __ATOMIC_RELAXED,
                                __HIP_MEMORY_SCOPE_AGENT) >= 64u) break;
          __builtin_amdgcn_s_sleep(2);
        }
      }
      __syncthreads();
    }
  }
  F1_STEP(Da, Db, Ca, Cb, 1, 1, 1);           // t = 49 (PAR 1; no A advance)
  // final epilogue for t = 49 (bank 1)
#pragma unroll
  for (int r = 0; r < 4; ++r) F1_EPI16(Da, r, hpA, r);
#pragma unroll
  for (int r = 0; r < 4; ++r) F1_EPI16(Db, r + 4, hpB, r);
}

// ---------------------------------------------------------------------------
// GEMM2 (r24 VERBATIM, best-measured): M=50*1024, N=128, K=1024, 5 slices
// (32x32x32). Decode q=id&7, nt=(id>>3)&3, tl=id>>5 (XCD co-location: the
// 4 nt-blocks sharing an A-panel have identical id%8, ids 8 apart).
// A = h1sc [t][o16][b][o_lo] (16B/lane coalesced). LDS-staged B (wave w
// stages slice w, wave 0 also slice 4), double-buffered. Output = EXACT
// int48 split planes (i32 low + i16 high; |T| < 2^47).
// ---------------------------------------------------------------------------
__global__ __launch_bounds__(256, 3) void gemm2_kernel(
    const signed char* __restrict__ Bf, const signed char* __restrict__ h1sc,
    int* __restrict__ T2L, short* __restrict__ T2H) {
  __shared__ i32x4 bls[2][NSL][64];
  int tid = threadIdx.x, lane = tid & 63, wv = tid >> 6;
  int id = (int)blockIdx.x;
  int q  = id & 7;                     // XCD pin (id%8 = q for all nt)
  int nt = (id >> 3) & 3;              // 0..3
  int tl = id >> 5;                    // 0..49
  int mt = (q << 2) + wv;              // 0..31
  const i32x4* Ar = (const i32x4*)h1sc
      + ((size_t)tl * 64 + (lane >> 5)) * 1024 + mt * 32 + (lane & 31);
  const i32x4* Bp = (const i32x4*)Bf + lane;
  const bool st4 = (wv == 0);
#define B2_IDX(s, kc) ((size_t)(((s) * 4 + nt) * 32 + (kc)) * 64)

  i32x16 C[NSL];
#pragma unroll
  for (int s = 0; s < NSL; ++s)
#pragma unroll
    for (int i = 0; i < 16; ++i) C[s][i] = 0;

  i32x4 sa = Bp[B2_IDX(wv, 0)];
  i32x4 sb; if (st4) sb = Bp[B2_IDX(4, 0)];
  i32x4 a0 = Ar[0];
  i32x4 a1 = Ar[2048];
  i32x4 a2;
  bls[0][wv][lane] = sa;
  if (st4) bls[0][4][lane] = sb;
  sa = Bp[B2_IDX(wv, 1)];
  if (st4) sb = Bp[B2_IDX(4, 1)];
  __syncthreads();

  for (int kc = 0; kc < 32; ++kc) {
    const int cur = kc & 1, nxt = cur ^ 1;
    if (kc + 1 < 32) {
      bls[nxt][wv][lane] = sa;
      if (st4) bls[nxt][4][lane] = sb;
    }
    if (kc + 2 < 32) {
      sa = Bp[B2_IDX(wv, kc + 2)];
      if (st4) sb = Bp[B2_IDX(4, kc + 2)];
      a2 = Ar[(size_t)(kc + 2) * 2048];
    }
    i32x4 b0 = bls[cur][0][lane], b1 = bls[cur][1][lane], b2 = bls[cur][2][lane];
    i32x4 b3 = bls[cur][3][lane], b4 = bls[cur][4][lane];
    C[0] = __builtin_amdgcn_mfma_i32_32x32x32_i8(a0, b0, C[0], 0, 0, 0);
    C[1] = __builtin_amdgcn_mfma_i32_32x32x32_i8(a0, b1, C[1], 0, 0, 0);
    C[2] = __builtin_amdgcn_mfma_i32_32x32x32_i8(a0, b2, C[2], 0, 0, 0);
    C[3] = __builtin_amdgcn_mfma_i32_32x32x32_i8(a0, b3, C[3], 0, 0, 0);
    C[4] = __builtin_amdgcn_mfma_i32_32x32x32_i8(a0, b4, C[4], 0, 0, 0);
    a0 = a1; a1 = a2;
    __syncthreads();
  }

  int o = nt * 32 + (lane & 31);
  int rb = 4 * (lane >> 5);
#pragma unroll
  for (int r = 0; r < 16; ++r) {
    int row = (r & 3) + 8 * (r >> 2) + rb;
    int b = mt * 32 + row;
    long long T = (long long)C[4][r];
    T = (T << 8) + (long long)C[3][r];
    T = (T << 8) + (long long)C[2][r];
    T = (T << 8) + (long long)C[1][r];
    T = (T << 8) + (long long)C[0][r];
    size_t i0 = ((size_t)tl * 1024 + b) * 128 + o;
    T2L[i0] = (int)T;
    T2H[i0] = (short)(T >> 32);
  }
}

// ---------------------------------------------------------------------------
// rec2: layer-2 membrane recurrence + AvgPool(10) + pPLI accumulator.
// T = (Th<<32) + (u32)Tl reconstruct (exact int48); next-step planes
// prefetched before the current update (LLC latency off the serial chain).
// ---------------------------------------------------------------------------
__global__ __launch_bounds__(256) void rec2_kernel(
    const int* __restrict__ T2L, const short* __restrict__ T2H,
    double* __restrict__ h2m_st,
    signed char* __restrict__ h2s_st, double* __restrict__ acc_st,
    const float* __restrict__ tauv, const float* __restrict__ acct,
    float* __restrict__ out) {
  __shared__ signed char sp[256];
  int tid = threadIdx.x;
  int b = blockIdx.x * 2 + (tid >> 7);
  int o = tid & 127;
  double alpha = 1.0 / (1.0 + exp(-(double)tauv[0]));
  double adec  = 1.0 / (1.0 + exp(-(double)acct[0]));
  double m = 0.5, s = 0.0, accv = 0.0;
  bool isPool = (o < 10);
  const int*   Lp = T2L + (size_t)b * 128 + o;   // + tl*131072 per step
  const short* Hp = T2H + (size_t)b * 128 + o;
  int   Tl = Lp[0];
  short Th = Hp[0];
  for (int tl = 0; tl < NSTEPS; ++tl) {
    int Tl2 = 0; short Th2 = 0;
    if (tl + 1 < NSTEPS) {                   // prefetch next step's planes
      Tl2 = Lp[(size_t)(tl + 1) * 131072];
      Th2 = Hp[(size_t)(tl + 1) * 131072];
    }
    long long T = ((long long)Th << 32) + (long long)(unsigned int)Tl;
    double I = (double)T * 0x1p-40;
    m = (s != 0.0 ? 0.0 : m * alpha) + I;
    bool spkb = (m - 1.0) >= 0.0;
    s = spkb ? 1.0 : 0.0;
    sp[tid] = spkb ? 1 : 0;
    __syncthreads();
    if (isPool) {
      int base = tid & 128;
      int isum = 0;
#pragma unroll
      for (int k = 0; k < 10; ++k) isum += sp[base + o * 10 + k];
      accv = accv * adec + (double)isum / 10.0;
      if (tl == NSTEPS - 1) out[b * 10 + o] = (float)accv;
    }
    __syncthreads();
    Tl = Tl2; Th = Th2;
  }
  h2m_st[(size_t)b * 128 + o] = m;
  h2s_st[(size_t)b * 128 + o] = (signed char)(s != 0.0 ? 1 : 0);
  if (isPool) acc_st[b * 10 + o] = accv;
}

// ---------------------------------------------------------------------------
extern "C" void kernel_launch(void* const* d_in, const int* in_sizes, int n_in,
                              void* d_out, int out_size, void* d_ws, size_t ws_size,
                              hipStream_t stream) {
  const float* x    = (const float*)d_in[0];
  const float* W1   = (const float*)d_in[1];
  const float* W2   = (const float*)d_in[2];
  const float* tau0 = (const float*)d_in[3];
  const float* tauv = (const float*)d_in[4];
  const float* acct = (const float*)d_in[5];
  float* out = (float*)d_out;
  char*  ws  = (char*)d_ws;

  signed char* B1     = (signed char*)(ws + OFF_B1);
  signed char* B2     = (signed char*)(ws + OFF_B2);
  signed char* Af     = (signed char*)(ws + OFF_AF);
  signed char* h1sc   = (signed char*)(ws + OFF_H1SC);
  int*         T2L    = (int*)(ws + OFF_T2L);
  short*       T2H    = (short*)(ws + OFF_T2H);
  double*      h2m_st = (double*)(ws + OFF_H2M);
  signed char* h2s_st = (signed char*)(ws + OFF_H2S);
  double*      acc_st = (double*)(ws + OFF_ACC);
  unsigned int* bar   = (unsigned int*)(ws + OFF_BAR);
  i32x4*       Afv    = (i32x4*)Af;

  // dynamic LDS for fused1 (53,248 B; attribute kept for safety)
  static bool attr_done = false;
  if (!attr_done) {
    (void)hipFuncSetAttribute((const void*)fused1_kernel,
                              hipFuncAttributeMaxDynamicSharedMemorySize,
                              53248);
    attr_done = true;
  }

  // 1) weight digit prep (3840 blocks) + spikegen for ALL 50 steps (10,400)
  setup_kernel<<<PREP_BLOCKS + SPK_BLOCKS, 256, 0, stream>>>(
      W1, W2, B1, B2, x, Afv, bar);

  // 2) time-fused layer 1: all 50 steps, membranes register-resident
  fused1_kernel<<<256, 512, 53248, stream>>>(B1, Afv, h1sc, tau0, bar);

  // 3) layer 2 GEMM over all 50 steps (XCD-swizzled, int48 split planes)
  gemm2_kernel<<<4 * NSTEPS * 8, 256, 0, stream>>>(B2, h1sc, T2L, T2H);

  // 4) layer 2 recurrence + pooling + accumulator (prefetched planes)
  rec2_kernel<<<512, 256, 0, stream>>>(
      T2L, T2H, h2m_st, h2s_st, acc_st, tauv, acct, out);
}